// Round 7
// baseline (737.647 us; speedup 1.0000x reference)
//
#include <hip/hip_runtime.h>
#include <stdint.h>

#define BB 8192
#define NN 50

typedef _Float16 half8 __attribute__((ext_vector_type(8)));
typedef float floatx4 __attribute__((ext_vector_type(4)));

union FragU { uint4 u; half8 h; };
static __device__ __forceinline__ half8 u2h(uint4 u) { FragU f; f.u = u; return f.h; }

static __device__ __forceinline__ uint32_t pk2u(float a, float b) {
    auto p = __builtin_amdgcn_cvt_pkrtz(a, b);
    uint32_t u; __builtin_memcpy(&u, &p, 4); return u;
}

#define MFMA(A, B, C) __builtin_amdgcn_mfma_f32_16x16x32_f16((A), (B), (C), 0, 0, 0)

static __device__ __forceinline__ float frcp(float x) {
#if __has_builtin(__builtin_amdgcn_rcpf)
    return __builtin_amdgcn_rcpf(x);
#else
    return 1.0f / x;
#endif
}
static __device__ __forceinline__ float fexp2(float x) {
#if __has_builtin(__builtin_amdgcn_exp2f)
    return __builtin_amdgcn_exp2f(x);
#else
    return __expf(0.69314718056f * x);
#endif
}

// Barrier-free 8-item waves. Each wave owns 8 items end-to-end: builds x,
// transposes x/h through its PRIVATE LDS slot (implicit lgkmcnt waits only --
// R0-proven pattern), runs all 12 gate tiles itself. No inter-wave exchange,
// no per-step barrier. 2048 waves = 2 fully independent waves/SIMD: each
// wave's stalls hide under the other's work (no lockstep coupling).
// Lanes 8-15 mirror lanes 0-7 (i8); MFMA cols 8-15 are discarded duplicates.
// VGPR budget (R2 lesson): whh in regs (96, critical h-path); wih/wtA/bias/
// W_feat in block-shared LDS (latency-tolerant reads). Scales folded into
// weights (R5). One __syncthreads at init only.
__global__ __launch_bounds__(256, 2)
void dygkt9(const float* __restrict__ nodef, const float* __restrict__ edgef,
            const int* __restrict__ src_ids, const int* __restrict__ dst_ids,
            const float* __restrict__ times,
            const int* __restrict__ s_nids, const int* __restrict__ s_eids,
            const float* __restrict__ s_ts,
            const int* __restrict__ d_nids, const int* __restrict__ d_eids,
            const float* __restrict__ d_ts,
            const float* __restrict__ W_feat, const float* __restrict__ b_feat,
            const float* __restrict__ W_edge, const float* __restrict__ b_edge,
            const float* __restrict__ W_time, const float* __restrict__ b_time,
            const float* __restrict__ W_str,  const float* __restrict__ b_str,
            const float* __restrict__ W_out,  const float* __restrict__ b_out,
            const float* __restrict__ time_w, const float* __restrict__ time_b,
            const float* __restrict__ sWih, const float* __restrict__ sWhh,
            const float* __restrict__ sbih, const float* __restrict__ sbhh,
            const float* __restrict__ dWih, const float* __restrict__ dWhh,
            const float* __restrict__ dbih, const float* __restrict__ dbhh,
            float* __restrict__ out)
{
    __shared__ uint4 wihL[24][64];                      // scaled Wih A-frags (24.5 KB)
    __shared__ uint4 wfA[8][64];                        // W_feat^T A-frags (8 KB)
    __shared__ uint4 wtAL[4][64];                       // bundle A-frags (4 KB)
    __shared__ floatx4 biasL[16][4];                    // gate-bias C-inits [idx][g] (1 KB)
    __shared__ __align__(16) _Float16 xtr[4][9 * 72];   // per-wave x^T (row 8 = dump)
    __shared__ __align__(16) _Float16 htr[4][9 * 72];   // per-wave h^T (row 8 = dump)

    const int tid = threadIdx.x, w = tid >> 6, lane = tid & 63;
    const int g = lane >> 4, i16 = lane & 15, i8 = lane & 7;
    const int ri = (i16 < 8) ? i16 : 8;                 // write row (8 = dump)
    const bool is_src = (blockIdx.x & 1) == 0;
    const int b = (int)(blockIdx.x >> 1) * 32 + w * 8 + i8;   // this lane's item

    const float SRZ = -1.44269504089f;   // -log2e: sigmoid(x)=rcp(1+exp2(SRZ*x))
    const float SN  =  2.88539008178f;   // 2*log2e: tanh(x)=1-2*rcp(exp2(SN*x)+1)
    const floatx4 z4 = {0, 0, 0, 0};

    const float* WI = is_src ? sWih : dWih;
    const float* WH = is_src ? sWhh : dWhh;
    const float* BI = is_src ? sbih : dbih;
    const float* BH = is_src ? sbhh : dbhh;

    // ---- stage block-shared LDS ----
    for (int q = tid; q < 512; q += 256) {
        int l = q & 63, tt = q >> 6;
        int kh = tt >> 2, mt = tt & 3, gg = l >> 4, ii = l & 15;
        float v[8];
        #pragma unroll
        for (int j = 0; j < 8; ++j)
            v[j] = W_feat[(32 * kh + 8 * gg + j) * 64 + 16 * mt + ii];
        wfA[tt][l] = make_uint4(pk2u(v[0],v[1]), pk2u(v[2],v[3]), pk2u(v[4],v[5]), pk2u(v[6],v[7]));
    }
    {
        int l = tid & 63, mt = tid >> 6;
        int gg = l >> 4, ii = l & 15;
        float v[8];
        #pragma unroll
        for (int j = 0; j < 8; ++j) {
            int k = 8 * gg + j, dim = 16 * mt + ii;
            float x = 0.0f;
            if (k < 16)       x = W_time[k * 64 + dim];
            else if (k == 16) x = W_edge[dim];
            else if (k == 17) x = W_str[dim];
            else if (k == 18) x = b_edge[dim] + b_time[dim];
            else if (k == 19) x = is_src ? (b_feat[dim] + 2.0f * b_str[dim]) : b_str[dim];
            else if (k == 20) x = b_feat[dim];
            v[j] = x;
        }
        wtAL[mt][l] = make_uint4(pk2u(v[0],v[1]), pk2u(v[2],v[3]), pk2u(v[4],v[5]), pk2u(v[6],v[7]));
    }
    for (int q = tid; q < 1536; q += 256) {
        int l = q & 63, idx = q >> 6;
        int gt = idx >> 3, rem = idx & 7, mt = rem >> 1, kh = rem & 1;
        float s = (gt == 2) ? SN : SRZ;
        int gg = l >> 4, ii = l & 15;
        int row = 64 * gt + 16 * mt + ii;
        const float* p = WI + (size_t)row * 64 + 32 * kh + 8 * gg;
        float4 a = *(const float4*)p, c = *(const float4*)(p + 4);
        wihL[idx][l] = make_uint4(pk2u(s*a.x,s*a.y), pk2u(s*a.z,s*a.w),
                                  pk2u(s*c.x,s*c.y), pk2u(s*c.z,s*c.w));
    }
    if (tid < 64) {
        int idx = tid >> 2, gg = tid & 3;
        int which = idx >> 2, mt = idx & 3;
        int base = 16 * mt + 4 * gg;
        floatx4 v;
        #pragma unroll
        for (int r = 0; r < 4; ++r) {
            float x;
            if (which == 0)      x = SRZ * (BI[base + r] + BH[base + r]);
            else if (which == 1) x = SRZ * (BI[64 + base + r] + BH[64 + base + r]);
            else if (which == 2) x = SN * BI[128 + base + r];
            else                 x = SN * BH[128 + base + r];
            v[r] = x;
        }
        biasL[idx][gg] = v;
    }
    for (int q = tid; q < 4 * 9 * 72 / 2; q += 256) ((uint32_t*)htr)[q] = 0u;

    // ---- per-thread whh frags (scaled; critical path -> registers) ----
    uint4 whh[3][4][2];
    #pragma unroll
    for (int gt = 0; gt < 3; ++gt) {
        const float s = (gt == 2) ? SN : SRZ;
        #pragma unroll
        for (int mt = 0; mt < 4; ++mt)
            #pragma unroll
            for (int kh = 0; kh < 2; ++kh) {
                int row = 64 * gt + 16 * mt + i16;
                const float* p = WH + (size_t)row * 64 + 32 * kh + 8 * g;
                float4 a = *(const float4*)p, c = *(const float4*)(p + 4);
                whh[gt][mt][kh] = make_uint4(pk2u(s*a.x,s*a.y), pk2u(s*a.z,s*a.w),
                                             pk2u(s*c.x,s*c.y), pk2u(s*c.z,s*c.w));
            }
    }

    // ---- per-item scalars (lanes 8-15 mirror lanes 0-7 via i8) ----
    const int* pn = (is_src ? s_nids : d_nids) + (size_t)b * NN;
    const int* pe = (is_src ? s_eids : d_eids) + (size_t)b * NN;
    const float* pt = (is_src ? s_ts : d_ts) + (size_t)b * NN;
    const float tqL = times[b];
    const int didL = dst_ids[b];
    const int oid = is_src ? didL : src_ids[b];
    const float dskill = is_src ? nodef[(size_t)didL * 64] : 0.0f;
    float twc[8], tbc[8];
    #pragma unroll
    for (int j = 0; j < 8; ++j) {
        int k = 8 * (g & 1) + j;
        twc[j] = time_w[k]; tbc[j] = time_b[k];
    }

    __syncthreads();   // staged LDS + htr zeros visible (ONLY block barrier)

    // ---- prime gather(0) ----
    int nidC = pn[0], eidC = pe[0];
    float tsC = pt[0];
    float e0C = edgef[4 * (size_t)eidC];
    float4 nfa = {0,0,0,0}, nfb = {0,0,0,0}, nfc = {0,0,0,0}, nfd = {0,0,0,0};
    if (is_src) {
        const float* rp = nodef + (size_t)nidC * 64 + 8 * g;
        nfa = *(const float4*)rp;        nfb = *(const float4*)(rp + 4);
        nfc = *(const float4*)(rp + 32); nfd = *(const float4*)(rp + 36);
    }

    floatx4 hM[4] = {z4, z4, z4, z4};
    _Float16* xp = xtr[w];
    _Float16* hp = htr[w];

    for (int t = 0; t < NN; ++t) {
        int nidN = 0, eidN = 0; float tsN = 0.0f;
        if (t + 1 < NN) { nidN = pn[t + 1]; eidN = pe[t + 1]; tsN = pt[t + 1]; }

        // ---- B-frag: [tenc(16) | e0, sf, 1, 1, 0...] ----
        float nsk = __shfl(nfa.x, i8);
        float sf = ((nidC == oid) ? 1.0f : 0.0f) +
                   ((is_src && nsk == dskill) ? 1.0f : 0.0f);
        float delta = tqL - tsC;
        uint4 tb4;
        if (g < 2) {
            float cv[8];
            #pragma unroll
            for (int j = 0; j < 8; ++j) cv[j] = __cosf(delta * twc[j] + tbc[j]);
            tb4 = make_uint4(pk2u(cv[0],cv[1]), pk2u(cv[2],cv[3]), pk2u(cv[4],cv[5]), pk2u(cv[6],cv[7]));
        } else if (g == 2) {
            tb4 = make_uint4(pk2u(e0C, sf), pk2u(1.0f, 1.0f), 0u, 0u);
        } else {
            tb4 = make_uint4(0u, 0u, 0u, 0u);
        }
        half8 tB = u2h(tb4);

        // ---- x rows (all 4 tiles) -> private slot ----
        if (is_src) {
            uint4 nf0 = make_uint4(pk2u(nfa.x,nfa.y), pk2u(nfa.z,nfa.w), pk2u(nfb.x,nfb.y), pk2u(nfb.z,nfb.w));
            uint4 nf1 = make_uint4(pk2u(nfc.x,nfc.y), pk2u(nfc.z,nfc.w), pk2u(nfd.x,nfd.y), pk2u(nfd.z,nfd.w));
            half8 nB0 = u2h(nf0), nB1 = u2h(nf1);
            #pragma unroll
            for (int mt = 0; mt < 4; ++mt) {
                floatx4 a = MFMA(u2h(wfA[mt][lane]), nB0, z4);
                a = MFMA(u2h(wfA[4 + mt][lane]), nB1, a);
                a = MFMA(u2h(wtAL[mt][lane]), tB, a);
                *(uint2*)&xp[ri * 72 + 16 * mt + 4 * g] =
                    make_uint2(pk2u(a[0], a[1]), pk2u(a[2], a[3]));
            }
        } else {
            #pragma unroll
            for (int mt = 0; mt < 4; ++mt) {
                floatx4 a = MFMA(u2h(wtAL[mt][lane]), tB, z4);
                *(uint2*)&xp[ri * 72 + 16 * mt + 4 * g] =
                    make_uint2(pk2u(a[0], a[1]), pk2u(a[2], a[3]));
            }
        }

        // ---- issue gathers for t+1 (latency hidden under gates) ----
        float e0N = 0.0f; float4 na = {0,0,0,0}, nb = {0,0,0,0}, nc = {0,0,0,0}, nd = {0,0,0,0};
        if (t + 1 < NN) {
            e0N = edgef[4 * (size_t)eidN];
            if (is_src) {
                const float* rp = nodef + (size_t)nidN * 64 + 8 * g;
                na = *(const float4*)rp;        nb = *(const float4*)(rp + 4);
                nc = *(const float4*)(rp + 32); nd = *(const float4*)(rp + 36);
            }
        } else if (!is_src) {
            const float* rp = nodef + (size_t)didL * 64 + 8 * g;   // d-row for tail
            na = *(const float4*)rp;        nb = *(const float4*)(rp + 4);
            nc = *(const float4*)(rp + 32); nd = *(const float4*)(rp + 36);
        }

        // ---- x,h B-frags (wave-private; compiler inserts lgkm waits) ----
        half8 xB0 = u2h(*(const uint4*)&xp[i8 * 72 + 8 * g]);
        half8 xB1 = u2h(*(const uint4*)&xp[i8 * 72 + 32 + 8 * g]);
        half8 hB0 = u2h(*(const uint4*)&hp[i8 * 72 + 8 * g]);
        half8 hB1 = u2h(*(const uint4*)&hp[i8 * 72 + 32 + 8 * g]);

        // ---- gates, tile by tile (12 tiles x 4 MFMAs) ----
        #pragma unroll
        for (int mt = 0; mt < 4; ++mt) {
            floatx4 rg = MFMA(u2h(wihL[2 * mt + 0][lane]), xB0, biasL[mt][g]);
            rg = MFMA(u2h(wihL[2 * mt + 1][lane]), xB1, rg);
            rg = MFMA(u2h(whh[0][mt][0]), hB0, rg);
            rg = MFMA(u2h(whh[0][mt][1]), hB1, rg);
            floatx4 zg = MFMA(u2h(wihL[8 + 2 * mt + 0][lane]), xB0, biasL[4 + mt][g]);
            zg = MFMA(u2h(wihL[8 + 2 * mt + 1][lane]), xB1, zg);
            zg = MFMA(u2h(whh[1][mt][0]), hB0, zg);
            zg = MFMA(u2h(whh[1][mt][1]), hB1, zg);
            floatx4 ia = MFMA(u2h(wihL[16 + 2 * mt + 0][lane]), xB0, biasL[8 + mt][g]);
            ia = MFMA(u2h(wihL[16 + 2 * mt + 1][lane]), xB1, ia);
            floatx4 ha = MFMA(u2h(whh[2][mt][0]), hB0, biasL[12 + mt][g]);
            ha = MFMA(u2h(whh[2][mt][1]), hB1, ha);
            #pragma unroll
            for (int r = 0; r < 4; ++r) {
                float rr = frcp(1.0f + fexp2(rg[r]));
                float zz = frcp(1.0f + fexp2(zg[r]));
                float nn = 1.0f - 2.0f * frcp(fexp2(ia[r] + rr * ha[r]) + 1.0f);
                hM[mt][r] = nn + zz * (hM[mt][r] - nn);
            }
            *(uint2*)&hp[ri * 72 + 16 * mt + 4 * g] =
                make_uint2(pk2u(hM[mt][0], hM[mt][1]), pk2u(hM[mt][2], hM[mt][3]));
        }

        nidC = nidN; eidC = eidN; tsC = tsN; e0C = e0N;
        nfa = na; nfb = nb; nfc = nc; nfd = nd;
    }

    // ---- tail: delta=0 time proj + edge(eid=0) proj [+ node_f(did)+b_feat for dst] ----
    float e00 = edgef[0];
    uint4 tt4;
    if (g < 2) {
        float cv[8];
        #pragma unroll
        for (int j = 0; j < 8; ++j) cv[j] = __cosf(tbc[j]);
        tt4 = make_uint4(pk2u(cv[0],cv[1]), pk2u(cv[2],cv[3]), pk2u(cv[4],cv[5]), pk2u(cv[6],cv[7]));
    } else if (g == 2) {
        tt4 = make_uint4(pk2u(e00, 0.0f), pk2u(1.0f, 0.0f), pk2u(is_src ? 0.0f : 1.0f, 0.0f), 0u);
    } else {
        tt4 = make_uint4(0u, 0u, 0u, 0u);
    }
    half8 tT = u2h(tt4);

    floatx4 tacc[4];
    #pragma unroll
    for (int mt = 0; mt < 4; ++mt) tacc[mt] = MFMA(u2h(wtAL[mt][lane]), tT, z4);
    if (!is_src) {
        uint4 d0 = make_uint4(pk2u(nfa.x,nfa.y), pk2u(nfa.z,nfa.w), pk2u(nfb.x,nfb.y), pk2u(nfb.z,nfb.w));
        uint4 d1 = make_uint4(pk2u(nfc.x,nfc.y), pk2u(nfc.z,nfc.w), pk2u(nfd.x,nfd.y), pk2u(nfd.z,nfd.w));
        #pragma unroll
        for (int mt = 0; mt < 4; ++mt) {
            tacc[mt] = MFMA(u2h(wfA[mt][lane]), u2h(d0), tacc[mt]);
            tacc[mt] = MFMA(u2h(wfA[4 + mt][lane]), u2h(d1), tacc[mt]);
        }
    }

    // ---- e = h + tail -> private slot -> B-frags; out = e @ W_out + b_out ----
    #pragma unroll
    for (int mt = 0; mt < 4; ++mt) {
        floatx4 e = hM[mt] + tacc[mt];
        *(uint2*)&xp[ri * 72 + 16 * mt + 4 * g] =
            make_uint2(pk2u(e[0], e[1]), pk2u(e[2], e[3]));
    }
    half8 eB0 = u2h(*(const uint4*)&xp[i8 * 72 + 8 * g]);
    half8 eB1 = u2h(*(const uint4*)&xp[i8 * 72 + 32 + 8 * g]);

    const size_t obase = (is_src ? 0 : (size_t)BB * 64) + (size_t)b * 64;
    #pragma unroll
    for (int mt = 0; mt < 4; ++mt) {
        float v[8], u[8];
        #pragma unroll
        for (int j = 0; j < 8; ++j) {
            int m = 16 * mt + i16;
            v[j] = W_out[(8 * g + j) * 64 + m];
            u[j] = W_out[(32 + 8 * g + j) * 64 + m];
        }
        uint4 wo0 = make_uint4(pk2u(v[0],v[1]), pk2u(v[2],v[3]), pk2u(v[4],v[5]), pk2u(v[6],v[7]));
        uint4 wo1 = make_uint4(pk2u(u[0],u[1]), pk2u(u[2],u[3]), pk2u(u[4],u[5]), pk2u(u[6],u[7]));
        floatx4 bo;
        #pragma unroll
        for (int r = 0; r < 4; ++r) bo[r] = b_out[16 * mt + 4 * g + r];
        floatx4 o = MFMA(u2h(wo0), eB0, bo);
        o = MFMA(u2h(wo1), eB1, o);
        if (i16 < 8)
            *(floatx4*)(out + obase + 16 * mt + 4 * g) = o;
    }
}

extern "C" void kernel_launch(void* const* d_in, const int* in_sizes, int n_in,
                              void* d_out, int out_size, void* d_ws, size_t ws_size,
                              hipStream_t stream) {
    (void)in_sizes; (void)n_in; (void)d_ws; (void)ws_size; (void)out_size;
    const float* nodef  = (const float*)d_in[0];
    const float* edgef  = (const float*)d_in[1];
    const int*   srcid  = (const int*)  d_in[2];
    const int*   dstid  = (const int*)  d_in[3];
    const float* times  = (const float*)d_in[4];
    const int*   s_nids = (const int*)  d_in[5];
    const int*   s_eids = (const int*)  d_in[6];
    const float* s_ts   = (const float*)d_in[7];
    const int*   d_nids = (const int*)  d_in[8];
    const int*   d_eids = (const int*)  d_in[9];
    const float* d_ts   = (const float*)d_in[10];
    const float* W_feat = (const float*)d_in[11];
    const float* b_feat = (const float*)d_in[12];
    const float* W_edge = (const float*)d_in[13];
    const float* b_edge = (const float*)d_in[14];
    const float* W_time = (const float*)d_in[15];
    const float* b_time = (const float*)d_in[16];
    const float* W_str  = (const float*)d_in[17];
    const float* b_str  = (const float*)d_in[18];
    const float* W_out  = (const float*)d_in[19];
    const float* b_out  = (const float*)d_in[20];
    const float* time_w = (const float*)d_in[21];
    const float* time_b = (const float*)d_in[22];
    const float* sWih   = (const float*)d_in[23];
    const float* sWhh   = (const float*)d_in[24];
    const float* sbih   = (const float*)d_in[25];
    const float* sbhh   = (const float*)d_in[26];
    const float* dWih   = (const float*)d_in[27];
    const float* dWhh   = (const float*)d_in[28];
    const float* dbih   = (const float*)d_in[29];
    const float* dbhh   = (const float*)d_in[30];

    dim3 grid(512), block(256);
    dygkt9<<<grid, block, 0, stream>>>(
        nodef, edgef, srcid, dstid, times,
        s_nids, s_eids, s_ts, d_nids, d_eids, d_ts,
        W_feat, b_feat, W_edge, b_edge, W_time, b_time,
        W_str, b_str, W_out, b_out, time_w, time_b,
        sWih, sWhh, sbih, sbhh, dWih, dWhh, dbih, dbhh,
        (float*)d_out);
}

// Round 9
// 270.039 us; speedup vs baseline: 2.7316x; 2.7316x over previous
//
#include <hip/hip_runtime.h>
#include <stdint.h>

#define BB 8192
#define NN 50

typedef _Float16 half8 __attribute__((ext_vector_type(8)));
typedef float floatx4 __attribute__((ext_vector_type(4)));

union FragU { uint4 u; half8 h; };
static __device__ __forceinline__ half8 u2h(uint4 u) { FragU f; f.u = u; return f.h; }

static __device__ __forceinline__ uint32_t pk2u(float a, float b) {
    auto p = __builtin_amdgcn_cvt_pkrtz(a, b);
    uint32_t u; __builtin_memcpy(&u, &p, 4); return u;
}

#define MFMA(A, B, C) __builtin_amdgcn_mfma_f32_16x16x32_f16((A), (B), (C), 0, 0, 0)

static __device__ __forceinline__ float frcp(float x) {
#if __has_builtin(__builtin_amdgcn_rcpf)
    return __builtin_amdgcn_rcpf(x);
#else
    return 1.0f / x;
#endif
}
static __device__ __forceinline__ float fexp2(float x) {
#if __has_builtin(__builtin_amdgcn_exp2f)
    return __builtin_amdgcn_exp2f(x);
#else
    return __expf(0.69314718056f * x);
#endif
}

// Raw barrier: drain LDS ops only (no vmcnt(0) drain -> prefetch loads stay in flight).
static __device__ __forceinline__ void bar_lds() {
    asm volatile("s_waitcnt lgkmcnt(0)" ::: "memory");
    __builtin_amdgcn_s_barrier();
}

// R1 (127us, proven) + critical-path surgery, structure unchanged:
//  (a) per-step __shfl (ds_bpermute) removed -- neighbor skill prefetched as a
//      scalar gather one step ahead (same cache line as the nf row gather);
//  (b) B-frag build (sf/delta/8xcos/packs, ~300cyc dependent VALU) for step t+1
//      moved into the post-barrier gate phase: overlaps the 24 gate MFMAs on the
//      other pipe; inputs were gathered pre-barrier (~700cyc earlier, L2/L3-hot).
//      Pre-barrier segment is now just x-MFMAs + pack + write.
//  (c) sigmoid/tanh arg scales folded into Wih/Whh/bias (R5-proven safe).
// Barrier/race discipline identical to R1: one raw lgkm-only barrier per step,
// parity x slots + double-buffered h slots, gathers in flight across the barrier.
__global__ __launch_bounds__(128, 2)
void dygkt10(const float* __restrict__ nodef, const float* __restrict__ edgef,
             const int* __restrict__ src_ids, const int* __restrict__ dst_ids,
             const float* __restrict__ times,
             const int* __restrict__ s_nids, const int* __restrict__ s_eids,
             const float* __restrict__ s_ts,
             const int* __restrict__ d_nids, const int* __restrict__ d_eids,
             const float* __restrict__ d_ts,
             const float* __restrict__ W_feat, const float* __restrict__ b_feat,
             const float* __restrict__ W_edge, const float* __restrict__ b_edge,
             const float* __restrict__ W_time, const float* __restrict__ b_time,
             const float* __restrict__ W_str,  const float* __restrict__ b_str,
             const float* __restrict__ W_out,  const float* __restrict__ b_out,
             const float* __restrict__ time_w, const float* __restrict__ time_b,
             const float* __restrict__ sWih, const float* __restrict__ sWhh,
             const float* __restrict__ sbih, const float* __restrict__ sbhh,
             const float* __restrict__ dWih, const float* __restrict__ dWhh,
             const float* __restrict__ dbih, const float* __restrict__ dbhh,
             float* __restrict__ out)
{
    __shared__ uint4 wfA[8][64];                        // W_feat^T A-frags, 8 KB
    __shared__ uint4 woA[8][64];                        // W_out^T  A-frags, 8 KB
    __shared__ __align__(16) _Float16 xls[2][16 * 72];  // x^T parity slots
    __shared__ __align__(16) _Float16 hls[2][16 * 72];  // h^T double buffer

    const int tid = threadIdx.x, w = tid >> 6, lane = tid & 63;
    const int g = lane >> 4, i16 = lane & 15;
    const bool is_src = (blockIdx.x & 1) == 0;
    const int b = (int)(blockIdx.x >> 1) * 16 + i16;    // this lane's item

    const float SRZ = -1.44269504089f;   // -log2e: sigmoid(x)=rcp(1+exp2(SRZ*x))
    const float SN  =  2.88539008178f;   // 2*log2e: tanh(x)=1-2*rcp(exp2(SN*x)+1)
    const floatx4 z4 = {0, 0, 0, 0};

    // ---- stage W_feat^T / W_out^T A-frags into LDS; zero hls[0] ----
    for (int q = tid; q < 512; q += 128) {
        int l = q & 63, tt = q >> 6;
        int kh = tt >> 2, mt = tt & 3, gg = l >> 4, ii = l & 15;
        float v[8], u[8];
        #pragma unroll
        for (int j = 0; j < 8; ++j) {
            int k = 32 * kh + 8 * gg + j, m = 16 * mt + ii;
            v[j] = W_feat[k * 64 + m];
            u[j] = W_out[k * 64 + m];
        }
        wfA[tt][l] = make_uint4(pk2u(v[0],v[1]), pk2u(v[2],v[3]), pk2u(v[4],v[5]), pk2u(v[6],v[7]));
        woA[tt][l] = make_uint4(pk2u(u[0],u[1]), pk2u(u[2],u[3]), pk2u(u[4],u[5]), pk2u(u[6],u[7]));
    }
    for (int q = tid; q < 16 * 72 / 2; q += 128) ((uint32_t*)hls[0])[q] = 0u;

    // ---- GRU weight A-frags for OUR row tiles (scaled; gate 0=r,1=z,2=n) ----
    const float* WI = is_src ? sWih : dWih;
    const float* WH = is_src ? sWhh : dWhh;
    uint4 wih[6][2], whh[6][2];   // [gate*2+tq][kh]
    #pragma unroll
    for (int gt = 0; gt < 3; ++gt) {
        const float s = (gt == 2) ? SN : SRZ;
        #pragma unroll
        for (int tq = 0; tq < 2; ++tq)
            #pragma unroll
            for (int kh = 0; kh < 2; ++kh) {
                int row = 64 * gt + 16 * (2 * w + tq) + i16;
                const float* p = WI + (size_t)row * 64 + 32 * kh + 8 * g;
                float4 a = *(const float4*)p, c = *(const float4*)(p + 4);
                wih[gt * 2 + tq][kh] = make_uint4(pk2u(s*a.x,s*a.y), pk2u(s*a.z,s*a.w),
                                                  pk2u(s*c.x,s*c.y), pk2u(s*c.z,s*c.w));
                const float* qq = WH + (size_t)row * 64 + 32 * kh + 8 * g;
                float4 e = *(const float4*)qq, f = *(const float4*)(qq + 4);
                whh[gt * 2 + tq][kh] = make_uint4(pk2u(s*e.x,s*e.y), pk2u(s*e.z,s*e.w),
                                                  pk2u(s*f.x,s*f.y), pk2u(s*f.z,s*f.w));
            }
    }

    // ---- time/edge/struct/bias bundle A-frags (unscaled: feeds x, not gates) ----
    uint4 wtA[2];
    #pragma unroll
    for (int tq = 0; tq < 2; ++tq) {
        int mt = 2 * w + tq;
        float v[8];
        #pragma unroll
        for (int j = 0; j < 8; ++j) {
            int k = 8 * g + j, dim = 16 * mt + i16;
            float x = 0.0f;
            if (k < 16)       x = W_time[k * 64 + dim];
            else if (k == 16) x = W_edge[dim];
            else if (k == 17) x = W_str[dim];
            else if (k == 18) x = b_edge[dim] + b_time[dim];
            else if (k == 19) x = is_src ? (b_feat[dim] + 2.0f * b_str[dim]) : b_str[dim];
            else if (k == 20) x = b_feat[dim];
            v[j] = x;
        }
        wtA[tq] = make_uint4(pk2u(v[0],v[1]), pk2u(v[2],v[3]), pk2u(v[4],v[5]), pk2u(v[6],v[7]));
    }

    // ---- gate bias C-init vectors (scaled) ----
    const float* BI = is_src ? sbih : dbih;
    const float* BH = is_src ? sbhh : dbhh;
    floatx4 brz[4], bin[2], bhn[2];   // brz: [0..1]=r, [2..3]=z
    #pragma unroll
    for (int gz = 0; gz < 2; ++gz)
        #pragma unroll
        for (int tq = 0; tq < 2; ++tq) {
            int r0 = 64 * gz + 16 * (2 * w + tq) + 4 * g;
            floatx4 v;
            #pragma unroll
            for (int r = 0; r < 4; ++r) v[r] = SRZ * (BI[r0 + r] + BH[r0 + r]);
            brz[gz * 2 + tq] = v;
        }
    #pragma unroll
    for (int tq = 0; tq < 2; ++tq) {
        int r0 = 128 + 16 * (2 * w + tq) + 4 * g;
        floatx4 vi, vh;
        #pragma unroll
        for (int r = 0; r < 4; ++r) { vi[r] = SN * BI[r0 + r]; vh[r] = SN * BH[r0 + r]; }
        bin[tq] = vi; bhn[tq] = vh;
    }

    // ---- per-lane (per-item) scalars ----
    const int* pn = (is_src ? s_nids : d_nids) + (size_t)b * NN;
    const int* pe = (is_src ? s_eids : d_eids) + (size_t)b * NN;
    const float* pt = (is_src ? s_ts : d_ts) + (size_t)b * NN;
    const float tqL = times[b];
    const int didL = dst_ids[b];
    const int oid = is_src ? didL : src_ids[b];
    const float dskill = is_src ? nodef[(size_t)didL * 64] : 0.0f;
    float twc[8], tbc[8];
    #pragma unroll
    for (int j = 0; j < 8; ++j) {
        int k = 8 * (g & 1) + j;
        twc[j] = time_w[k]; tbc[j] = time_b[k];
    }

    __syncthreads();   // wfA/woA + hls[0] zeros visible

    // ---- prologue: gather(0) and build tb4C(0) ----
    float4 nfa = {0,0,0,0}, nfb = {0,0,0,0}, nfc = {0,0,0,0}, nfd = {0,0,0,0};
    uint4 tb4C;
    {
        int nid0 = pn[0], eid0 = pe[0];
        float ts0 = pt[0];
        float e00v = edgef[4 * (size_t)eid0];
        float nsk0 = 0.0f;
        if (is_src) {
            const float* rp = nodef + (size_t)nid0 * 64 + 8 * g;
            nfa = *(const float4*)rp;        nfb = *(const float4*)(rp + 4);
            nfc = *(const float4*)(rp + 32); nfd = *(const float4*)(rp + 36);
            nsk0 = nodef[(size_t)nid0 * 64];
        }
        float sf = ((nid0 == oid) ? 1.0f : 0.0f) +
                   ((is_src && nsk0 == dskill) ? 1.0f : 0.0f);
        float delta = tqL - ts0;
        if (g < 2) {
            float cv[8];
            #pragma unroll
            for (int j = 0; j < 8; ++j) cv[j] = __cosf(delta * twc[j] + tbc[j]);
            tb4C = make_uint4(pk2u(cv[0],cv[1]), pk2u(cv[2],cv[3]), pk2u(cv[4],cv[5]), pk2u(cv[6],cv[7]));
        } else if (g == 2) {
            tb4C = make_uint4(pk2u(e00v, sf), pk2u(1.0f, 1.0f), 0u, 0u);
        } else {
            tb4C = make_uint4(0u, 0u, 0u, 0u);
        }
    }

    floatx4 hM[2] = {z4, z4};
    int cur = 0;

    for (int t = 0; t < NN; ++t) {
        const bool hasn = (t + 1 < NN);
        // scalar prefetch for t+1
        int nidN = 0, eidN = 0; float tsN = 0.0f;
        if (hasn) { nidN = pn[t + 1]; eidN = pe[t + 1]; tsN = pt[t + 1]; }

        // ---- x rows for our tiles from tb4C (ready) + nf regs; -> xls[cur] ----
        {
            half8 tB = u2h(tb4C);
            if (is_src) {
                uint4 nf0 = make_uint4(pk2u(nfa.x,nfa.y), pk2u(nfa.z,nfa.w), pk2u(nfb.x,nfb.y), pk2u(nfb.z,nfb.w));
                uint4 nf1 = make_uint4(pk2u(nfc.x,nfc.y), pk2u(nfc.z,nfc.w), pk2u(nfd.x,nfd.y), pk2u(nfd.z,nfd.w));
                half8 nB0 = u2h(nf0), nB1 = u2h(nf1);
                #pragma unroll
                for (int tq = 0; tq < 2; ++tq) {
                    int mt = 2 * w + tq;
                    floatx4 a = MFMA(u2h(wfA[mt][lane]), nB0, z4);
                    a = MFMA(u2h(wfA[4 + mt][lane]), nB1, a);
                    floatx4 xacc = MFMA(u2h(wtA[tq]), tB, a);
                    *(uint2*)&xls[cur][i16 * 72 + 32 * w + 16 * tq + 4 * g] =
                        make_uint2(pk2u(xacc[0], xacc[1]), pk2u(xacc[2], xacc[3]));
                }
            } else {
                #pragma unroll
                for (int tq = 0; tq < 2; ++tq) {
                    floatx4 xacc = MFMA(u2h(wtA[tq]), tB, z4);
                    *(uint2*)&xls[cur][i16 * 72 + 32 * w + 16 * tq + 4 * g] =
                        make_uint2(pk2u(xacc[0], xacc[1]), pk2u(xacc[2], xacc[3]));
                }
            }
        }

        // ---- issue gathers for t+1 (incl. skill scalar); in flight across barrier ----
        float e0N = 0.0f, nskN = 0.0f;
        float4 na = {0,0,0,0}, nb = {0,0,0,0}, nc = {0,0,0,0}, nd = {0,0,0,0};
        if (hasn) {
            e0N = edgef[4 * (size_t)eidN];
            if (is_src) {
                const float* rp = nodef + (size_t)nidN * 64 + 8 * g;
                na = *(const float4*)rp;        nb = *(const float4*)(rp + 4);
                nc = *(const float4*)(rp + 32); nd = *(const float4*)(rp + 36);
                nskN = nodef[(size_t)nidN * 64];
            }
        }

        bar_lds();

        // ---- full x and h B-frags ----
        half8 xB0 = u2h(*(const uint4*)&xls[cur][i16 * 72 + 8 * g]);
        half8 xB1 = u2h(*(const uint4*)&xls[cur][i16 * 72 + 32 + 8 * g]);
        half8 hB0 = u2h(*(const uint4*)&hls[cur][i16 * 72 + 8 * g]);
        half8 hB1 = u2h(*(const uint4*)&hls[cur][i16 * 72 + 32 + 8 * g]);

        // ---- gate GEMMs (24 MFMAs; scaled weights/biases) ----
        floatx4 rg[2], zg[2], ia[2], ha[2];
        #pragma unroll
        for (int tq = 0; tq < 2; ++tq) {
            floatx4 a = MFMA(u2h(wih[tq][0]), xB0, brz[tq]);
            a = MFMA(u2h(wih[tq][1]), xB1, a);
            a = MFMA(u2h(whh[tq][0]), hB0, a);
            rg[tq] = MFMA(u2h(whh[tq][1]), hB1, a);
        }
        #pragma unroll
        for (int tq = 0; tq < 2; ++tq) {
            floatx4 a = MFMA(u2h(wih[2 + tq][0]), xB0, brz[2 + tq]);
            a = MFMA(u2h(wih[2 + tq][1]), xB1, a);
            a = MFMA(u2h(whh[2 + tq][0]), hB0, a);
            zg[tq] = MFMA(u2h(whh[2 + tq][1]), hB1, a);
        }
        #pragma unroll
        for (int tq = 0; tq < 2; ++tq) {
            floatx4 a = MFMA(u2h(wih[4 + tq][0]), xB0, bin[tq]);
            ia[tq] = MFMA(u2h(wih[4 + tq][1]), xB1, a);
            floatx4 c = MFMA(u2h(whh[4 + tq][0]), hB0, bhn[tq]);
            ha[tq] = MFMA(u2h(whh[4 + tq][1]), hB1, c);
        }

        // ---- B-build(t+1): pure VALU, overlaps the gate MFMAs above ----
        uint4 tb4N = make_uint4(0u, 0u, 0u, 0u);
        if (hasn) {
            float sf = ((nidN == oid) ? 1.0f : 0.0f) +
                       ((is_src && nskN == dskill) ? 1.0f : 0.0f);
            float delta = tqL - tsN;
            if (g < 2) {
                float cv[8];
                #pragma unroll
                for (int j = 0; j < 8; ++j) cv[j] = __cosf(delta * twc[j] + tbc[j]);
                tb4N = make_uint4(pk2u(cv[0],cv[1]), pk2u(cv[2],cv[3]), pk2u(cv[4],cv[5]), pk2u(cv[6],cv[7]));
            } else if (g == 2) {
                tb4N = make_uint4(pk2u(e0N, sf), pk2u(1.0f, 1.0f), 0u, 0u);
            }
        }

        // ---- gate math (scales pre-folded) ----
        #pragma unroll
        for (int tq = 0; tq < 2; ++tq)
            #pragma unroll
            for (int r = 0; r < 4; ++r) {
                float rr = frcp(1.0f + fexp2(rg[tq][r]));
                float zz = frcp(1.0f + fexp2(zg[tq][r]));
                float vv = ia[tq][r] + rr * ha[tq][r];
                float nn = 1.0f - 2.0f * frcp(fexp2(vv) + 1.0f);
                hM[tq][r] = nn + zz * (hM[tq][r] - nn);
            }

        // ---- write h(t+1) to the other buffer ----
        #pragma unroll
        for (int tq = 0; tq < 2; ++tq)
            *(uint2*)&hls[cur ^ 1][i16 * 72 + 32 * w + 16 * tq + 4 * g] =
                make_uint2(pk2u(hM[tq][0], hM[tq][1]), pk2u(hM[tq][2], hM[tq][3]));

        // rotate
        tb4C = tb4N;
        nfa = na; nfb = nb; nfc = nc; nfd = nd;
        cur ^= 1;
    }

    // ---- tail: delta=0 time proj + edge(eid=0) proj [+ node_f(did)+b_feat for dst] ----
    float e00 = edgef[0];
    uint4 tt4;
    if (g < 2) {
        float cv[8];
        #pragma unroll
        for (int j = 0; j < 8; ++j) cv[j] = __cosf(tbc[j]);
        tt4 = make_uint4(pk2u(cv[0],cv[1]), pk2u(cv[2],cv[3]), pk2u(cv[4],cv[5]), pk2u(cv[6],cv[7]));
    } else if (g == 2) {
        tt4 = make_uint4(pk2u(e00, 0.0f), pk2u(1.0f, 0.0f), pk2u(is_src ? 0.0f : 1.0f, 0.0f), 0u);
    } else {
        tt4 = make_uint4(0u, 0u, 0u, 0u);
    }
    half8 tT = u2h(tt4);

    floatx4 tacc[2];
    #pragma unroll
    for (int tq = 0; tq < 2; ++tq) tacc[tq] = MFMA(u2h(wtA[tq]), tT, z4);
    if (!is_src) {
        const float* rp = nodef + (size_t)didL * 64 + 8 * g;
        float4 da = *(const float4*)rp,        db = *(const float4*)(rp + 4);
        float4 dc = *(const float4*)(rp + 32), dd = *(const float4*)(rp + 36);
        uint4 d0 = make_uint4(pk2u(da.x,da.y), pk2u(da.z,da.w), pk2u(db.x,db.y), pk2u(db.z,db.w));
        uint4 d1 = make_uint4(pk2u(dc.x,dc.y), pk2u(dc.z,dc.w), pk2u(dd.x,dd.y), pk2u(dd.z,dd.w));
        #pragma unroll
        for (int tq = 0; tq < 2; ++tq) {
            int mt = 2 * w + tq;
            tacc[tq] = MFMA(u2h(wfA[mt][lane]), u2h(d0), tacc[tq]);
            tacc[tq] = MFMA(u2h(wfA[4 + mt][lane]), u2h(d1), tacc[tq]);
        }
    }

    // ---- e = h + tail -> LDS; out = e @ W_out + b_out via MFMA ----
    #pragma unroll
    for (int tq = 0; tq < 2; ++tq) {
        floatx4 e = hM[tq] + tacc[tq];
        *(uint2*)&xls[0][i16 * 72 + 32 * w + 16 * tq + 4 * g] =
            make_uint2(pk2u(e[0], e[1]), pk2u(e[2], e[3]));
    }
    bar_lds();
    half8 eB0 = u2h(*(const uint4*)&xls[0][i16 * 72 + 8 * g]);
    half8 eB1 = u2h(*(const uint4*)&xls[0][i16 * 72 + 32 + 8 * g]);

    const size_t obase = (is_src ? 0 : (size_t)BB * 64) + (size_t)b * 64;
    #pragma unroll
    for (int tq = 0; tq < 2; ++tq) {
        int mt = 2 * w + tq;
        floatx4 bo;
        #pragma unroll
        for (int r = 0; r < 4; ++r) bo[r] = b_out[16 * mt + 4 * g + r];
        floatx4 o = MFMA(u2h(woA[mt][lane]), eB0, bo);
        o = MFMA(u2h(woA[4 + mt][lane]), eB1, o);
        #pragma unroll
        for (int r = 0; r < 4; ++r)
            out[obase + 16 * mt + 4 * g + r] = o[r];
    }
}

extern "C" void kernel_launch(void* const* d_in, const int* in_sizes, int n_in,
                              void* d_out, int out_size, void* d_ws, size_t ws_size,
                              hipStream_t stream) {
    (void)in_sizes; (void)n_in; (void)d_ws; (void)ws_size; (void)out_size;
    const float* nodef  = (const float*)d_in[0];
    const float* edgef  = (const float*)d_in[1];
    const int*   srcid  = (const int*)  d_in[2];
    const int*   dstid  = (const int*)  d_in[3];
    const float* times  = (const float*)d_in[4];
    const int*   s_nids = (const int*)  d_in[5];
    const int*   s_eids = (const int*)  d_in[6];
    const float* s_ts   = (const float*)d_in[7];
    const int*   d_nids = (const int*)  d_in[8];
    const int*   d_eids = (const int*)  d_in[9];
    const float* d_ts   = (const float*)d_in[10];
    const float* W_feat = (const float*)d_in[11];
    const float* b_feat = (const float*)d_in[12];
    const float* W_edge = (const float*)d_in[13];
    const float* b_edge = (const float*)d_in[14];
    const float* W_time = (const float*)d_in[15];
    const float* b_time = (const float*)d_in[16];
    const float* W_str  = (const float*)d_in[17];
    const float* b_str  = (const float*)d_in[18];
    const float* W_out  = (const float*)d_in[19];
    const float* b_out  = (const float*)d_in[20];
    const float* time_w = (const float*)d_in[21];
    const float* time_b = (const float*)d_in[22];
    const float* sWih   = (const float*)d_in[23];
    const float* sWhh   = (const float*)d_in[24];
    const float* sbih   = (const float*)d_in[25];
    const float* sbhh   = (const float*)d_in[26];
    const float* dWih   = (const float*)d_in[27];
    const float* dWhh   = (const float*)d_in[28];
    const float* dbih   = (const float*)d_in[29];
    const float* dbhh   = (const float*)d_in[30];

    dim3 grid(1024), block(128);
    dygkt10<<<grid, block, 0, stream>>>(
        nodef, edgef, srcid, dstid, times,
        s_nids, s_eids, s_ts, d_nids, d_eids, d_ts,
        W_feat, b_feat, W_edge, b_edge, W_time, b_time,
        W_str, b_str, W_out, b_out, time_w, time_b,
        sWih, sWhh, sbih, sbhh, dWih, dWhh, dbih, dbhh,
        (float*)d_out);
}

// Round 10
// 241.944 us; speedup vs baseline: 3.0488x; 1.1161x over previous
//
#include <hip/hip_runtime.h>
#include <stdint.h>

#define BB 8192
#define NN 50

typedef _Float16 half8 __attribute__((ext_vector_type(8)));
typedef float floatx4 __attribute__((ext_vector_type(4)));

union FragU { uint4 u; half8 h; };
static __device__ __forceinline__ half8 u2h(uint4 u) { FragU f; f.u = u; return f.h; }

static __device__ __forceinline__ uint32_t pk2u(float a, float b) {
    auto p = __builtin_amdgcn_cvt_pkrtz(a, b);
    uint32_t u; __builtin_memcpy(&u, &p, 4); return u;
}

#define MFMA(A, B, C) __builtin_amdgcn_mfma_f32_16x16x32_f16((A), (B), (C), 0, 0, 0)

static __device__ __forceinline__ float frcp(float x) {
#if __has_builtin(__builtin_amdgcn_rcpf)
    return __builtin_amdgcn_rcpf(x);
#else
    return 1.0f / x;
#endif
}
static __device__ __forceinline__ float fexp2(float x) {
#if __has_builtin(__builtin_amdgcn_exp2f)
    return __builtin_amdgcn_exp2f(x);
#else
    return __expf(0.69314718056f * x);
#endif
}

// Raw barrier: drain LDS ops only (no vmcnt(0) drain -> prefetch loads stay in flight).
static __device__ __forceinline__ void bar_lds() {
    asm volatile("s_waitcnt lgkmcnt(0)" ::: "memory");
    __builtin_amdgcn_s_barrier();
}

// R1/dygkt4 (127us rocprof, best of 7 measured structures) with ONLY two
// chain-shortening micro-fixes; phase order byte-identical to R1:
//  (a) per-step __shfl (ds_bpermute, ~30cyc in the pre-barrier B-build chain)
//      replaced by a skill scalar prefetched one step ahead (same cache line
//      as the nf row gather);
//  (c) sigmoid/tanh argument scales folded into Wih/Whh/biases (removes 24
//      dependent v_muls from the post-MFMA gate-math chain; numerics validated
//      in R5+R9, absmax unchanged).
// R9 lesson: do NOT move the B-build post-barrier -- the gate-MFMA region
// (~150cyc) is shorter than the B-build (~300cyc); it extends the serial phase.
__global__ __launch_bounds__(128, 2)
void dygkt11(const float* __restrict__ nodef, const float* __restrict__ edgef,
             const int* __restrict__ src_ids, const int* __restrict__ dst_ids,
             const float* __restrict__ times,
             const int* __restrict__ s_nids, const int* __restrict__ s_eids,
             const float* __restrict__ s_ts,
             const int* __restrict__ d_nids, const int* __restrict__ d_eids,
             const float* __restrict__ d_ts,
             const float* __restrict__ W_feat, const float* __restrict__ b_feat,
             const float* __restrict__ W_edge, const float* __restrict__ b_edge,
             const float* __restrict__ W_time, const float* __restrict__ b_time,
             const float* __restrict__ W_str,  const float* __restrict__ b_str,
             const float* __restrict__ W_out,  const float* __restrict__ b_out,
             const float* __restrict__ time_w, const float* __restrict__ time_b,
             const float* __restrict__ sWih, const float* __restrict__ sWhh,
             const float* __restrict__ sbih, const float* __restrict__ sbhh,
             const float* __restrict__ dWih, const float* __restrict__ dWhh,
             const float* __restrict__ dbih, const float* __restrict__ dbhh,
             float* __restrict__ out)
{
    __shared__ uint4 wfA[8][64];                        // W_feat^T A-frags, 8 KB
    __shared__ uint4 woA[8][64];                        // W_out^T  A-frags, 8 KB
    __shared__ __align__(16) _Float16 xls[2][16 * 72];  // double-buffered x^T
    __shared__ __align__(16) _Float16 hls[2][16 * 72];  // double-buffered h^T

    const int tid = threadIdx.x, w = tid >> 6, lane = tid & 63;
    const int g = lane >> 4, i16 = lane & 15;
    const bool is_src = blockIdx.x < 512;
    const int b = (int)(blockIdx.x & 511) * 16 + i16;   // this lane's item

    const float SRZ = -1.44269504089f;   // -log2e: sigmoid(x)=rcp(1+exp2(SRZ*x))
    const float SN  =  2.88539008178f;   // 2*log2e: tanh(x)=1-2*rcp(exp2(SN*x)+1)
    const floatx4 z4 = {0, 0, 0, 0};

    // ---- stage W_feat^T / W_out^T A-frags into LDS; zero hls[0] ----
    for (int q = tid; q < 512; q += 128) {
        int l = q & 63, tt = q >> 6;
        int kh = tt >> 2, mt = tt & 3, gg = l >> 4, ii = l & 15;
        float v[8], u[8];
        #pragma unroll
        for (int j = 0; j < 8; ++j) {
            int k = 32 * kh + 8 * gg + j, m = 16 * mt + ii;
            v[j] = W_feat[k * 64 + m];
            u[j] = W_out[k * 64 + m];
        }
        wfA[tt][l] = make_uint4(pk2u(v[0],v[1]), pk2u(v[2],v[3]), pk2u(v[4],v[5]), pk2u(v[6],v[7]));
        woA[tt][l] = make_uint4(pk2u(u[0],u[1]), pk2u(u[2],u[3]), pk2u(u[4],u[5]), pk2u(u[6],u[7]));
    }
    for (int q = tid; q < 16 * 72 / 2; q += 128) ((uint32_t*)hls[0])[q] = 0u;

    // ---- GRU weight A-frags for OUR row tiles (scaled; gate 0=r,1=z,2=n) ----
    const float* WI = is_src ? sWih : dWih;
    const float* WH = is_src ? sWhh : dWhh;
    uint4 wih[6][2], whh[6][2];   // [gate*2+tq][kh]
    #pragma unroll
    for (int gt = 0; gt < 3; ++gt) {
        const float s = (gt == 2) ? SN : SRZ;
        #pragma unroll
        for (int tq = 0; tq < 2; ++tq)
            #pragma unroll
            for (int kh = 0; kh < 2; ++kh) {
                int row = 64 * gt + 16 * (2 * w + tq) + i16;
                const float* p = WI + (size_t)row * 64 + 32 * kh + 8 * g;
                float4 a = *(const float4*)p, c = *(const float4*)(p + 4);
                wih[gt * 2 + tq][kh] = make_uint4(pk2u(s*a.x,s*a.y), pk2u(s*a.z,s*a.w),
                                                  pk2u(s*c.x,s*c.y), pk2u(s*c.z,s*c.w));
                const float* qq = WH + (size_t)row * 64 + 32 * kh + 8 * g;
                float4 e = *(const float4*)qq, f = *(const float4*)(qq + 4);
                whh[gt * 2 + tq][kh] = make_uint4(pk2u(s*e.x,s*e.y), pk2u(s*e.z,s*e.w),
                                                  pk2u(s*f.x,s*f.y), pk2u(s*f.z,s*f.w));
            }
    }

    // ---- time/edge/struct/bias bundle A-frags (unscaled: feeds x, not gates) ----
    uint4 wtA[2];
    #pragma unroll
    for (int tq = 0; tq < 2; ++tq) {
        int mt = 2 * w + tq;
        float v[8];
        #pragma unroll
        for (int j = 0; j < 8; ++j) {
            int k = 8 * g + j, dim = 16 * mt + i16;
            float x = 0.0f;
            if (k < 16)       x = W_time[k * 64 + dim];
            else if (k == 16) x = W_edge[dim];
            else if (k == 17) x = W_str[dim];
            else if (k == 18) x = b_edge[dim] + b_time[dim];
            else if (k == 19) x = is_src ? (b_feat[dim] + 2.0f * b_str[dim]) : b_str[dim];
            else if (k == 20) x = b_feat[dim];
            v[j] = x;
        }
        wtA[tq] = make_uint4(pk2u(v[0],v[1]), pk2u(v[2],v[3]), pk2u(v[4],v[5]), pk2u(v[6],v[7]));
    }

    // ---- gate bias C-init vectors (scaled) ----
    const float* BI = is_src ? sbih : dbih;
    const float* BH = is_src ? sbhh : dbhh;
    floatx4 brz[4], bin[2], bhn[2];   // brz: [0..1]=r, [2..3]=z
    #pragma unroll
    for (int gz = 0; gz < 2; ++gz)
        #pragma unroll
        for (int tq = 0; tq < 2; ++tq) {
            int r0 = 64 * gz + 16 * (2 * w + tq) + 4 * g;
            floatx4 v;
            #pragma unroll
            for (int r = 0; r < 4; ++r) v[r] = SRZ * (BI[r0 + r] + BH[r0 + r]);
            brz[gz * 2 + tq] = v;
        }
    #pragma unroll
    for (int tq = 0; tq < 2; ++tq) {
        int r0 = 128 + 16 * (2 * w + tq) + 4 * g;
        floatx4 vi, vh;
        #pragma unroll
        for (int r = 0; r < 4; ++r) { vi[r] = SN * BI[r0 + r]; vh[r] = SN * BH[r0 + r]; }
        bin[tq] = vi; bhn[tq] = vh;
    }

    // ---- per-lane (per-item) scalars ----
    const int* pn = (is_src ? s_nids : d_nids) + (size_t)b * NN;
    const int* pe = (is_src ? s_eids : d_eids) + (size_t)b * NN;
    const float* pt = (is_src ? s_ts : d_ts) + (size_t)b * NN;
    const float tqL = times[b];
    const int didL = dst_ids[b];
    const int oid = is_src ? didL : src_ids[b];
    const float dskill = is_src ? nodef[(size_t)didL * 64] : 0.0f;
    float twc[8], tbc[8];
    #pragma unroll
    for (int j = 0; j < 8; ++j) {
        int k = 8 * (g & 1) + j;
        twc[j] = time_w[k]; tbc[j] = time_b[k];
    }

    __syncthreads();   // wfA/woA + hls[0] zeros visible (only block-wide sync)

    // ---- prime prefetch for t = 0 (incl. skill scalar -- replaces __shfl) ----
    int nidC = pn[0], eidC = pe[0];
    float tsC = pt[0];
    float e0C = edgef[4 * (size_t)eidC];
    float nskC = 0.0f;
    float4 nfa = {0,0,0,0}, nfb = {0,0,0,0}, nfc = {0,0,0,0}, nfd = {0,0,0,0};
    if (is_src) {
        const float* rp = nodef + (size_t)nidC * 64 + 8 * g;
        nfa = *(const float4*)rp;        nfb = *(const float4*)(rp + 4);
        nfc = *(const float4*)(rp + 32); nfd = *(const float4*)(rp + 36);
        nskC = nodef[(size_t)nidC * 64];
    }

    floatx4 hM[2] = {z4, z4};
    int cur = 0;

    for (int t = 0; t < NN; ++t) {
        // scalar prefetch for t+1
        int nidN = 0, eidN = 0; float tsN = 0.0f;
        if (t + 1 < NN) { nidN = pn[t + 1]; eidN = pe[t + 1]; tsN = pt[t + 1]; }

        // ---- B-frag: [tenc(16) | e0, sf, 1, 1, 0...] (nskC: no __shfl) ----
        float sf = ((nidC == oid) ? 1.0f : 0.0f) +
                   ((is_src && nskC == dskill) ? 1.0f : 0.0f);
        float delta = tqL - tsC;
        uint4 tb4;
        if (g < 2) {
            float cv[8];
            #pragma unroll
            for (int j = 0; j < 8; ++j) cv[j] = __cosf(delta * twc[j] + tbc[j]);
            tb4 = make_uint4(pk2u(cv[0],cv[1]), pk2u(cv[2],cv[3]), pk2u(cv[4],cv[5]), pk2u(cv[6],cv[7]));
        } else if (g == 2) {
            tb4 = make_uint4(pk2u(e0C, sf), pk2u(1.0f, 1.0f), 0u, 0u);
        } else {
            tb4 = make_uint4(0u, 0u, 0u, 0u);
        }
        half8 tB = u2h(tb4);

        // ---- x rows for our tiles ----
        if (is_src) {
            uint4 nf0 = make_uint4(pk2u(nfa.x,nfa.y), pk2u(nfa.z,nfa.w), pk2u(nfb.x,nfb.y), pk2u(nfb.z,nfb.w));
            uint4 nf1 = make_uint4(pk2u(nfc.x,nfc.y), pk2u(nfc.z,nfc.w), pk2u(nfd.x,nfd.y), pk2u(nfd.z,nfd.w));
            half8 nB0 = u2h(nf0), nB1 = u2h(nf1);
            #pragma unroll
            for (int tq = 0; tq < 2; ++tq) {
                int mt = 2 * w + tq;
                floatx4 a = MFMA(u2h(wfA[mt][lane]), nB0, z4);
                a = MFMA(u2h(wfA[4 + mt][lane]), nB1, a);
                floatx4 xacc = MFMA(u2h(wtA[tq]), tB, a);
                *(uint2*)&xls[cur][i16 * 72 + 32 * w + 16 * tq + 4 * g] =
                    make_uint2(pk2u(xacc[0], xacc[1]), pk2u(xacc[2], xacc[3]));
            }
        } else {
            #pragma unroll
            for (int tq = 0; tq < 2; ++tq) {
                floatx4 xacc = MFMA(u2h(wtA[tq]), tB, z4);
                *(uint2*)&xls[cur][i16 * 72 + 32 * w + 16 * tq + 4 * g] =
                    make_uint2(pk2u(xacc[0], xacc[1]), pk2u(xacc[2], xacc[3]));
            }
        }

        // ---- issue gathers for t+1 (incl. skill); in flight across the barrier ----
        float e0N = 0.0f, nskN = 0.0f;
        float4 na = {0,0,0,0}, nb = {0,0,0,0}, nc = {0,0,0,0}, nd = {0,0,0,0};
        if (t + 1 < NN) {
            e0N = edgef[4 * (size_t)eidN];
            if (is_src) {
                const float* rp = nodef + (size_t)nidN * 64 + 8 * g;
                na = *(const float4*)rp;        nb = *(const float4*)(rp + 4);
                nc = *(const float4*)(rp + 32); nd = *(const float4*)(rp + 36);
                nskN = nodef[(size_t)nidN * 64];
            }
        }

        bar_lds();

        // ---- full x and h B-frags (rows 0..63, both waves' halves) ----
        half8 xB0 = u2h(*(const uint4*)&xls[cur][i16 * 72 + 8 * g]);
        half8 xB1 = u2h(*(const uint4*)&xls[cur][i16 * 72 + 32 + 8 * g]);
        half8 hB0 = u2h(*(const uint4*)&hls[cur][i16 * 72 + 8 * g]);
        half8 hB1 = u2h(*(const uint4*)&hls[cur][i16 * 72 + 32 + 8 * g]);

        // ---- gate GEMMs for our row tiles (24 MFMAs; scaled weights) ----
        floatx4 rg[2], zg[2], ia[2], ha[2];
        #pragma unroll
        for (int tq = 0; tq < 2; ++tq) {
            floatx4 a = MFMA(u2h(wih[tq][0]), xB0, brz[tq]);
            a = MFMA(u2h(wih[tq][1]), xB1, a);
            a = MFMA(u2h(whh[tq][0]), hB0, a);
            rg[tq] = MFMA(u2h(whh[tq][1]), hB1, a);
        }
        #pragma unroll
        for (int tq = 0; tq < 2; ++tq) {
            floatx4 a = MFMA(u2h(wih[2 + tq][0]), xB0, brz[2 + tq]);
            a = MFMA(u2h(wih[2 + tq][1]), xB1, a);
            a = MFMA(u2h(whh[2 + tq][0]), hB0, a);
            zg[tq] = MFMA(u2h(whh[2 + tq][1]), hB1, a);
        }
        #pragma unroll
        for (int tq = 0; tq < 2; ++tq) {
            floatx4 a = MFMA(u2h(wih[4 + tq][0]), xB0, bin[tq]);
            ia[tq] = MFMA(u2h(wih[4 + tq][1]), xB1, a);
            floatx4 c = MFMA(u2h(whh[4 + tq][0]), hB0, bhn[tq]);
            ha[tq] = MFMA(u2h(whh[4 + tq][1]), hB1, c);
        }

        // ---- gate math (scales pre-folded into weights/biases) ----
        #pragma unroll
        for (int tq = 0; tq < 2; ++tq)
            #pragma unroll
            for (int r = 0; r < 4; ++r) {
                float rr = frcp(1.0f + fexp2(rg[tq][r]));
                float zz = frcp(1.0f + fexp2(zg[tq][r]));
                float nn = 1.0f - 2.0f * frcp(fexp2(ia[tq][r] + rr * ha[tq][r]) + 1.0f);
                hM[tq][r] = nn + zz * (hM[tq][r] - nn);
            }

        // ---- write our h rows to the NEXT buffer ----
        #pragma unroll
        for (int tq = 0; tq < 2; ++tq)
            *(uint2*)&hls[cur ^ 1][i16 * 72 + 32 * w + 16 * tq + 4 * g] =
                make_uint2(pk2u(hM[tq][0], hM[tq][1]), pk2u(hM[tq][2], hM[tq][3]));

        cur ^= 1;
        nidC = nidN; eidC = eidN; tsC = tsN; e0C = e0N; nskC = nskN;
        nfa = na; nfb = nb; nfc = nc; nfd = nd;
    }

    // ---- tail: delta=0 time proj + edge(eid=0) proj [+ node_f(did)+b_feat for dst] ----
    float e00 = edgef[0];
    uint4 tt4;
    if (g < 2) {
        float cv[8];
        #pragma unroll
        for (int j = 0; j < 8; ++j) cv[j] = __cosf(tbc[j]);
        tt4 = make_uint4(pk2u(cv[0],cv[1]), pk2u(cv[2],cv[3]), pk2u(cv[4],cv[5]), pk2u(cv[6],cv[7]));
    } else if (g == 2) {
        tt4 = make_uint4(pk2u(e00, 0.0f), pk2u(1.0f, 0.0f), pk2u(is_src ? 0.0f : 1.0f, 0.0f), 0u);
    } else {
        tt4 = make_uint4(0u, 0u, 0u, 0u);
    }
    half8 tT = u2h(tt4);

    floatx4 tacc[2];
    #pragma unroll
    for (int tq = 0; tq < 2; ++tq) tacc[tq] = MFMA(u2h(wtA[tq]), tT, z4);
    if (!is_src) {
        const float* rp = nodef + (size_t)didL * 64 + 8 * g;
        float4 da = *(const float4*)rp,        db = *(const float4*)(rp + 4);
        float4 dc = *(const float4*)(rp + 32), dd = *(const float4*)(rp + 36);
        uint4 d0 = make_uint4(pk2u(da.x,da.y), pk2u(da.z,da.w), pk2u(db.x,db.y), pk2u(db.z,db.w));
        uint4 d1 = make_uint4(pk2u(dc.x,dc.y), pk2u(dc.z,dc.w), pk2u(dd.x,dd.y), pk2u(dd.z,dd.w));
        #pragma unroll
        for (int tq = 0; tq < 2; ++tq) {
            int mt = 2 * w + tq;
            tacc[tq] = MFMA(u2h(wfA[mt][lane]), u2h(d0), tacc[tq]);
            tacc[tq] = MFMA(u2h(wfA[4 + mt][lane]), u2h(d1), tacc[tq]);
        }
    }

    // ---- e = h + tail -> LDS; out = e @ W_out + b_out via MFMA ----
    #pragma unroll
    for (int tq = 0; tq < 2; ++tq) {
        floatx4 e = hM[tq] + tacc[tq];
        *(uint2*)&xls[0][i16 * 72 + 32 * w + 16 * tq + 4 * g] =
            make_uint2(pk2u(e[0], e[1]), pk2u(e[2], e[3]));
    }
    bar_lds();
    half8 eB0 = u2h(*(const uint4*)&xls[0][i16 * 72 + 8 * g]);
    half8 eB1 = u2h(*(const uint4*)&xls[0][i16 * 72 + 32 + 8 * g]);

    const size_t obase = (is_src ? 0 : (size_t)BB * 64) + (size_t)b * 64;
    #pragma unroll
    for (int tq = 0; tq < 2; ++tq) {
        int mt = 2 * w + tq;
        floatx4 bo;
        #pragma unroll
        for (int r = 0; r < 4; ++r) bo[r] = b_out[16 * mt + 4 * g + r];
        floatx4 o = MFMA(u2h(woA[mt][lane]), eB0, bo);
        o = MFMA(u2h(woA[4 + mt][lane]), eB1, o);
        #pragma unroll
        for (int r = 0; r < 4; ++r)
            out[obase + 16 * mt + 4 * g + r] = o[r];
    }
}

extern "C" void kernel_launch(void* const* d_in, const int* in_sizes, int n_in,
                              void* d_out, int out_size, void* d_ws, size_t ws_size,
                              hipStream_t stream) {
    (void)in_sizes; (void)n_in; (void)d_ws; (void)ws_size; (void)out_size;
    const float* nodef  = (const float*)d_in[0];
    const float* edgef  = (const float*)d_in[1];
    const int*   srcid  = (const int*)  d_in[2];
    const int*   dstid  = (const int*)  d_in[3];
    const float* times  = (const float*)d_in[4];
    const int*   s_nids = (const int*)  d_in[5];
    const int*   s_eids = (const int*)  d_in[6];
    const float* s_ts   = (const float*)d_in[7];
    const int*   d_nids = (const int*)  d_in[8];
    const int*   d_eids = (const int*)  d_in[9];
    const float* d_ts   = (const float*)d_in[10];
    const float* W_feat = (const float*)d_in[11];
    const float* b_feat = (const float*)d_in[12];
    const float* W_edge = (const float*)d_in[13];
    const float* b_edge = (const float*)d_in[14];
    const float* W_time = (const float*)d_in[15];
    const float* b_time = (const float*)d_in[16];
    const float* W_str  = (const float*)d_in[17];
    const float* b_str  = (const float*)d_in[18];
    const float* W_out  = (const float*)d_in[19];
    const float* b_out  = (const float*)d_in[20];
    const float* time_w = (const float*)d_in[21];
    const float* time_b = (const float*)d_in[22];
    const float* sWih   = (const float*)d_in[23];
    const float* sWhh   = (const float*)d_in[24];
    const float* sbih   = (const float*)d_in[25];
    const float* sbhh   = (const float*)d_in[26];
    const float* dWih   = (const float*)d_in[27];
    const float* dWhh   = (const float*)d_in[28];
    const float* dbih   = (const float*)d_in[29];
    const float* dbhh   = (const float*)d_in[30];

    dim3 grid(1024), block(128);
    dygkt11<<<grid, block, 0, stream>>>(
        nodef, edgef, srcid, dstid, times,
        s_nids, s_eids, s_ts, d_nids, d_eids, d_ts,
        W_feat, b_feat, W_edge, b_edge, W_time, b_time,
        W_str, b_str, W_out, b_out, time_w, time_b,
        sWih, sWhh, sbih, sbhh, dWih, dWhh, dbih, dbhh,
        (float*)d_out);
}